// Round 1
// baseline (2185.095 us; speedup 1.0000x reference)
//
#include <hip/hip_runtime.h>
#include <hip/hip_bf16.h>
#include <cstdint>
#include <cstddef>

typedef _Float16 f16_t;
typedef _Float16 h2    __attribute__((ext_vector_type(2)));
typedef _Float16 f16x8 __attribute__((ext_vector_type(8)));
typedef float    f32x4 __attribute__((ext_vector_type(4)));

#define MFMA_F16(A, Bv, Cv) __builtin_amdgcn_mfma_f32_16x16x32_f16((A), (Bv), (Cv), 0, 0, 0)

__device__ __forceinline__ float fdot2_(h2 a, h2 b, float c) {
#if __has_builtin(__builtin_amdgcn_fdot2)
  return __builtin_amdgcn_fdot2(a, b, c, false);
#else
  return c + (float)a[0] * (float)b[0] + (float)a[1] * (float)b[1];
#endif
}

// ---------------------------------------------------------------------------
// W fp32 -> f16 converters (run while target ws region is dead).
// ---------------------------------------------------------------------------
__global__ __launch_bounds__(256) void wconvA_kernel(
    const float* __restrict__ Wq, const float* __restrict__ Wk,
    const float* __restrict__ Wv, f16_t* __restrict__ dst)
{
  int idx = blockIdx.x * 256 + threadIdx.x;        // 98304 float4 tasks
  int src = idx >> 15, off = idx & 32767;
  const float* W = (src == 0) ? Wq : (src == 1) ? Wk : Wv;
  float4 a = *(const float4*)(W + (size_t)off * 4);
  f16_t* d = dst + (size_t)src * 131072 + (size_t)off * 4;
  d[0] = (f16_t)a.x; d[1] = (f16_t)a.y; d[2] = (f16_t)a.z; d[3] = (f16_t)a.w;
}

__global__ __launch_bounds__(256) void wconvB_kernel(
    const float* __restrict__ Wfc, f16_t* __restrict__ dst)
{
  int idx = blockIdx.x * 256 + threadIdx.x;        // 32768 float4 tasks
  float4 a = *(const float4*)(Wfc + (size_t)idx * 4);
  f16_t* d = dst + (size_t)idx * 4;
  d[0] = (f16_t)a.x; d[1] = (f16_t)a.y; d[2] = (f16_t)a.z; d[3] = (f16_t)a.w;
}

// ---------------------------------------------------------------------------
// Stage A: projections.  Block = 128 pixels; X staged ONCE (64 KB LDS, f16,
// [p][k=256] with chunk swizzle g ^ (p&7) ^ ((p>>3)&7)); loop 4 otiles inside;
// B-fragments gathered directly from L2-hot W_f16 (no LDS, no barriers).
// grid: [3 proj][4 b][128 ptile] = 1536 blocks x 256 thr
// ---------------------------------------------------------------------------
__global__ __launch_bounds__(256, 2) void proj_kernel(
    const float* __restrict__ xq, const float* __restrict__ xk, const float* __restrict__ xv,
    const f16_t* __restrict__ Wall,
    f16_t* __restrict__ qh, f16_t* __restrict__ kh, f16_t* __restrict__ vh)
{
  int bid = blockIdx.x;
  const int pt = bid & 127; bid >>= 7;
  const int b  = bid & 3;   bid >>= 2;
  const int proj = bid;

  const float* X = (proj == 0) ? xq : (proj == 1) ? xk : xv;
  const f16_t* Wf = Wall + (size_t)proj * 131072;
  f16_t* OUT     = (proj == 0) ? qh : (proj == 1) ? kh : vh;

  const int p0 = pt * 128;
  __shared__ __align__(16) f16_t Xl[128 * 256];  // 64 KB

  const int tid = threadIdx.x;
  const int lane = tid & 63, wv = tid >> 6;
  const int wp = (wv & 1) * 64, wo = (wv >> 1) * 64;
  const int l15 = lane & 15, q4 = lane >> 4;

  const size_t xbase = (size_t)b * 256 * 16384;

  // stage X tile [c=256][p=128] fp32 -> LDS [p][k] f16, c-pairs as h2
#pragma unroll
  for (int t = 0; t < 16; ++t) {
    int task = t * 256 + tid;            // 4096 tasks: (c2 128) x (p4 32)
    int c2 = task >> 5, p4 = task & 31;
    int c0 = c2 * 2;
    float4 a0 = *(const float4*)(X + xbase + (size_t)c0 * 16384 + p0 + p4 * 4);
    float4 a1 = *(const float4*)(X + xbase + (size_t)(c0 + 1) * 16384 + p0 + p4 * 4);
    const float* f0 = &a0.x; const float* f1 = &a1.x;
    int g = c0 >> 3;
#pragma unroll
    for (int i = 0; i < 4; ++i) {
      int p = p4 * 4 + i;
      int sw = (p & 7) ^ ((p >> 3) & 7);
      h2 val = (h2){(f16_t)f0[i], (f16_t)f1[i]};
      *(h2*)&Xl[(p << 8) + ((g ^ sw) << 3) + (c0 & 7)] = val;
    }
  }
  __syncthreads();

#pragma unroll 1
  for (int ot = 0; ot < 4; ++ot) {
    f32x4 acc[4][4];
#pragma unroll
    for (int i = 0; i < 4; ++i)
#pragma unroll
      for (int j = 0; j < 4; ++j) acc[i][j] = (f32x4){0.f, 0.f, 0.f, 0.f};

#pragma unroll
    for (int kc = 0; kc < 4; ++kc) {
#pragma unroll
      for (int ks = 0; ks < 2; ++ks) {
        const int gq = kc * 8 + ks * 4 + q4;     // chunk 0..31
        f16x8 af[4], bfr[4];
#pragma unroll
        for (int i = 0; i < 4; ++i) {
          int p = wp + i * 16 + l15;
          int sw = (p & 7) ^ ((p >> 3) & 7);
          int gs = (gq & 0x18) | ((gq ^ sw) & 7);
          af[i] = *(const f16x8*)&Xl[(p << 8) + (gs << 3)];
        }
#pragma unroll
        for (int j = 0; j < 4; ++j) {
          int o = ot * 128 + wo + j * 16 + l15;
          bfr[j] = *(const f16x8*)(Wf + (size_t)o * 256 + kc * 64 + ks * 32 + q4 * 8);
        }
#pragma unroll
        for (int i = 0; i < 4; ++i)
#pragma unroll
          for (int j = 0; j < 4; ++j)
            acc[i][j] = MFMA_F16(af[i], bfr[j], acc[i][j]);
      }
    }

#pragma unroll
    for (int i = 0; i < 4; ++i) {
#pragma unroll
      for (int j = 0; j < 4; ++j) {
        int o = ot * 128 + wo + j * 16 + l15;
        int nn = o >> 6, d = o & 63;
#pragma unroll
        for (int r = 0; r < 4; ++r) {
          int p = p0 + wp + i * 16 + q4 * 4 + r;
          OUT[(((size_t)b * 8 + nn) * 16384 + p) * 64 + d] = (f16_t)acc[i][j][r];
        }
      }
    }
  }
}

// ---------------------------------------------------------------------------
// Stage B: 7x7 local attention, online softmax, dy-paired.
// v2: 8 pixel rows per block (halves K/V halo re-fetch: 14 loaded rows / 8
// computed rows vs 12/4), 512 threads = (rp 4, w 64, dg 2); T14 async-STAGE
// split: next-row global loads issued into regs BEFORE compute, vmcnt-wait +
// LDS write AFTER compute (HBM latency hidden under the fdot2/fma phase).
// 2-slot LDS ring of K|V rows (70 px x 16 chunks x 16B, XOR swizzle); 14 its.
// Zero halo == reference zero padding (OOB logits 0 participate in softmax).
// grid: [4 b][8 n][16 rowoct][2 whalf] = 1024 blocks x 512 thr
// ---------------------------------------------------------------------------
__global__ __launch_bounds__(512, 6) void attn_kernel(
    const f16_t* __restrict__ qh, const f16_t* __restrict__ kh,
    const f16_t* __restrict__ vh, f16_t* __restrict__ ao)
{
  int bid = blockIdx.x;
  const int wh = bid & 1;  bid >>= 1;
  const int oc8 = bid & 15; bid >>= 4;
  const int n  = bid & 7;  bid >>= 3;
  const int b  = bid;
  const int h0 = oc8 * 8, w0 = wh * 64;

  const int tid = threadIdx.x;
  const int rp = tid >> 7;          // row-pair 0..3 (wave-uniform)
  const int w  = (tid >> 1) & 63;
  const int dg = tid & 1;           // 32-channel group
  const int dg4 = dg * 4;
  const int hA = h0 + 2 * rp, hB = hA + 1;

  const size_t headoff = ((size_t)b * 8 + n) * 16384 * 64;
  const f16_t* Qh = qh + headoff;
  const f16_t* Kh = kh + headoff;
  const f16_t* Vh = vh + headoff;

  __shared__ uint4 ring[2][70 * 16];  // [slot][pix*16 + (oc ^ (pix&15))]

  union Pack { uint4 u[4]; h2 h[16]; };

  Pack quA, quB;
  {
    const uint4* qa = (const uint4*)(Qh + ((size_t)hA * 128 + w0 + w) * 64 + dg * 32);
    const uint4* qb = (const uint4*)(Qh + ((size_t)hB * 128 + w0 + w) * 64 + dg * 32);
#pragma unroll
    for (int j = 0; j < 4; ++j) { quA.u[j] = qa[j]; quB.u[j] = qb[j]; }
  }

  const float cscale = 0.18033688011112042f;  // (1/8) * log2(e)

  float mA = -3.0e38f, lA = 0.f, mB = -3.0e38f, lB = 0.f;
  h2 ovA[16], ovB[16];
#pragma unroll
  for (int j = 0; j < 16; ++j) { ovA[j] = (h2){(f16_t)0.f, (f16_t)0.f}; ovB[j] = ovA[j]; }

  // preload first K/V row (h0-3) into slot 0 (direct: load + write)
  {
    const int r = h0 - 3;
    const bool rok = (r >= 0) && (r < 128);
#pragma unroll
    for (int t = 0; t < 3; ++t) {
      int task = t * 512 + tid;            // 70*16 = 1120 16B-chunk tasks
      if (task < 1120) {
        int pix = task >> 4, oc = task & 15;
        int ww = w0 + pix - 3;
        uint4 val = make_uint4(0u, 0u, 0u, 0u);
        if (rok && ww >= 0 && ww < 128) {
          const f16_t* src = (oc < 8)
              ? (Kh + ((size_t)r * 128 + ww) * 64 + oc * 8)
              : (Vh + ((size_t)r * 128 + ww) * 64 + (oc - 8) * 8);
          val = *(const uint4*)src;
        }
        ring[0][(pix << 4) + (oc ^ (pix & 15))] = val;
      }
    }
  }
  __syncthreads();

#pragma unroll 1
  for (int it = 0; it < 14; ++it) {
    // ---- issue next-row global loads into regs (no wait yet) ----
    uint4 rv0 = make_uint4(0u, 0u, 0u, 0u);
    uint4 rv1 = rv0, rv2 = rv0;
    const bool pf = (it < 13);
    if (pf) {
      const int r = h0 - 2 + it;
      const bool rok = (r >= 0) && (r < 128);
      {
        int task = tid;                       // pix 0..31
        int pix = task >> 4, oc = task & 15;
        int ww = w0 + pix - 3;
        if (rok && ww >= 0 && ww < 128)
          rv0 = *(const uint4*)((oc < 8)
              ? (Kh + ((size_t)r * 128 + ww) * 64 + oc * 8)
              : (Vh + ((size_t)r * 128 + ww) * 64 + (oc - 8) * 8));
      }
      {
        int task = 512 + tid;                 // pix 32..63
        int pix = task >> 4, oc = task & 15;
        int ww = w0 + pix - 3;
        if (rok && ww >= 0 && ww < 128)
          rv1 = *(const uint4*)((oc < 8)
              ? (Kh + ((size_t)r * 128 + ww) * 64 + oc * 8)
              : (Vh + ((size_t)r * 128 + ww) * 64 + (oc - 8) * 8));
      }
      {
        int task = 1024 + tid;                // pix 64..69 (partial)
        if (task < 1120) {
          int pix = task >> 4, oc = task & 15;
          int ww = w0 + pix - 3;
          if (rok && ww >= 0 && ww < 128)
            rv2 = *(const uint4*)((oc < 8)
                ? (Kh + ((size_t)r * 128 + ww) * 64 + oc * 8)
                : (Vh + ((size_t)r * 128 + ww) * 64 + (oc - 8) * 8));
        }
      }
    }

    // ---- compute vs current row ----
    const uint4* cur = ring[it & 1];
    const int dyA = it - 2 * rp;                        // wave-uniform
    const int dyB = dyA - 1;
    const bool aA = (dyA >= 0) && (dyA < 7);
    const bool aB = (dyB >= 0) && (dyB < 7);
    if (aA || aB) {
      // scores vs this k-row for both owned pixels
      float sA[7], sB[7];
#pragma unroll
      for (int dx = 0; dx < 7; ++dx) {
        const int pix = w + dx, sw = pix & 15, base = pix << 4;
        Pack ku;
        ku.u[0] = cur[base + ((dg4 + 0) ^ sw)];
        ku.u[1] = cur[base + ((dg4 + 1) ^ sw)];
        ku.u[2] = cur[base + ((dg4 + 2) ^ sw)];
        ku.u[3] = cur[base + ((dg4 + 3) ^ sw)];
        float accA = 0.f, accB = 0.f;
#pragma unroll
        for (int j = 0; j < 16; ++j) {
          accA = fdot2_(quA.h[j], ku.h[j], accA);
          accB = fdot2_(quB.h[j], ku.h[j], accB);
        }
        sA[dx] = accA; sB[dx] = accB;
      }
#pragma unroll
      for (int dx = 0; dx < 7; ++dx) {
        sA[dx] = (sA[dx] + __shfl_xor(sA[dx], 1)) * cscale;
        sB[dx] = (sB[dx] + __shfl_xor(sB[dx], 1)) * cscale;
      }

      // online softmax updates
      h2 eA[7], eB[7];
      if (aA) {
        float nm = mA;
#pragma unroll
        for (int dx = 0; dx < 7; ++dx) nm = fmaxf(nm, sA[dx]);
        float alpha = exp2f(mA - nm);
        mA = nm; lA *= alpha;
        f16_t ah = (f16_t)alpha; h2 a2 = (h2){ah, ah};
#pragma unroll
        for (int j = 0; j < 16; ++j) ovA[j] *= a2;
#pragma unroll
        for (int dx = 0; dx < 7; ++dx) {
          float e = exp2f(sA[dx] - mA);
          lA += e; f16_t eh = (f16_t)e; eA[dx] = (h2){eh, eh};
        }
      }
      if (aB) {
        float nm = mB;
#pragma unroll
        for (int dx = 0; dx < 7; ++dx) nm = fmaxf(nm, sB[dx]);
        float alpha = exp2f(mB - nm);
        mB = nm; lB *= alpha;
        f16_t ah = (f16_t)alpha; h2 a2 = (h2){ah, ah};
#pragma unroll
        for (int j = 0; j < 16; ++j) ovB[j] *= a2;
#pragma unroll
        for (int dx = 0; dx < 7; ++dx) {
          float e = exp2f(sB[dx] - mB);
          lB += e; f16_t eh = (f16_t)e; eB[dx] = (h2){eh, eh};
        }
      }

      // weighted V (chunk read shared by both pixels)
#pragma unroll
      for (int dx = 0; dx < 7; ++dx) {
        const int pix = w + dx, sw = pix & 15, base = pix << 4;
        Pack vu;
        vu.u[0] = cur[base + ((8 + dg4 + 0) ^ sw)];
        vu.u[1] = cur[base + ((8 + dg4 + 1) ^ sw)];
        vu.u[2] = cur[base + ((8 + dg4 + 2) ^ sw)];
        vu.u[3] = cur[base + ((8 + dg4 + 3) ^ sw)];
        if (aA) {
#pragma unroll
          for (int j = 0; j < 16; ++j) ovA[j] = eA[dx] * vu.h[j] + ovA[j];
        }
        if (aB) {
#pragma unroll
          for (int j = 0; j < 16; ++j) ovB[j] = eB[dx] * vu.h[j] + ovB[j];
        }
      }
    }

    // ---- write staged row to LDS (vmcnt waits happen here, after compute) ----
    if (pf) {
      uint4* nxt = ring[(it + 1) & 1];
      {
        int task = tid;
        int pix = task >> 4, oc = task & 15;
        nxt[(pix << 4) + (oc ^ (pix & 15))] = rv0;
      }
      {
        int task = 512 + tid;
        int pix = task >> 4, oc = task & 15;
        nxt[(pix << 4) + (oc ^ (pix & 15))] = rv1;
      }
      {
        int task = 1024 + tid;
        if (task < 1120) {
          int pix = task >> 4, oc = task & 15;
          nxt[(pix << 4) + (oc ^ (pix & 15))] = rv2;
        }
      }
    }
    __syncthreads();
  }

  // epilogue: normalize, store 32 f16 channels per owned pixel
  {
    float inv = 1.0f / lA; f16_t ih = (f16_t)inv; h2 i2 = (h2){ih, ih};
    Pack ou;
#pragma unroll
    for (int j = 0; j < 16; ++j) ou.h[j] = ovA[j] * i2;
    uint4* d4 = (uint4*)(ao + (((size_t)b * 16384) + (size_t)hA * 128 + (w0 + w)) * 512 + n * 64 + dg * 32);
    d4[0] = ou.u[0]; d4[1] = ou.u[1]; d4[2] = ou.u[2]; d4[3] = ou.u[3];
  }
  {
    float inv = 1.0f / lB; f16_t ih = (f16_t)inv; h2 i2 = (h2){ih, ih};
    Pack ou;
#pragma unroll
    for (int j = 0; j < 16; ++j) ou.h[j] = ovB[j] * i2;
    uint4* d4 = (uint4*)(ao + (((size_t)b * 16384) + (size_t)hB * 128 + (w0 + w)) * 512 + n * 64 + dg * 32);
    d4[0] = ou.u[0]; d4[1] = ou.u[1]; d4[2] = ou.u[2]; d4[3] = ou.u[3];
  }
}

// ---------------------------------------------------------------------------
// Stage C: o = Wfc @ ao + residual, LayerNorm over C=256, fused.
// ao tile staged ONCE ([p=64][k=512] f16, 64 KB); A-fragments of Wfc_f16
// gathered directly from L2-hot global.  2 barriers/block.
// grid: [4 b][256 ptile(64)] = 1024 blocks x 256 thr
// ---------------------------------------------------------------------------
__global__ __launch_bounds__(256, 2) void fc_ln_kernel(
    const f16_t* __restrict__ ao, const f16_t* __restrict__ Wfc16,
    const float* __restrict__ resid, const float* __restrict__ lnw,
    const float* __restrict__ lnb, float* __restrict__ outp)
{
  int bid = blockIdx.x;
  const int pt = bid & 255;
  const int b = bid >> 8;
  const int p0 = pt * 64;

  const int tid = threadIdx.x;
  const int lane = tid & 63, wv = tid >> 6;
  const int c0w = wv * 64;
  const int l15 = lane & 15, q4 = lane >> 4;

  __shared__ __align__(16) f16_t Bl[64 * 512];  // ao tile [p][k], 64 KB
  __shared__ float lnws[256], lnbs[256];
  __shared__ float red[2][4][64];

  lnws[tid] = lnw[tid];
  lnbs[tid] = lnb[tid];

  // stage full ao tile once
#pragma unroll
  for (int t = 0; t < 16; ++t) {
    int task = t * 256 + tid;            // 4096 tasks: (p 64) x (g 64)
    int p = task >> 6, g = task & 63;
    uint4 v4 = *(const uint4*)(ao + ((size_t)b * 16384 + p0 + p) * 512 + g * 8);
    int gs = (g & 0x38) | ((g ^ (p & 7)) & 7);
    *(uint4*)&Bl[(p << 9) + (gs << 3)] = v4;
  }
  __syncthreads();

  f32x4 acc[4][4];
#pragma unroll
  for (int i = 0; i < 4; ++i)
#pragma unroll
    for (int j = 0; j < 4; ++j) acc[i][j] = (f32x4){0.f, 0.f, 0.f, 0.f};

#pragma unroll 1
  for (int kc = 0; kc < 8; ++kc) {
#pragma unroll
    for (int ks = 0; ks < 2; ++ks) {
      const int gq = kc * 8 + ks * 4 + q4;     // chunk 0..63
      f16x8 af[4], bfr[4];
#pragma unroll
      for (int i = 0; i < 4; ++i) {
        int c = c0w + i * 16 + l15;
        af[i] = *(const f16x8*)(Wfc16 + (size_t)c * 512 + kc * 64 + ks * 32 + q4 * 8);
      }
#pragma unroll
      for (int j = 0; j < 4; ++j) {
        int p = j * 16 + l15;
        int gs = (gq & 0x38) | ((gq ^ (p & 7)) & 7);
        bfr[j] = *(const f16x8*)&Bl[(p << 9) + (gs << 3)];
      }
#pragma unroll
      for (int i = 0; i < 4; ++i)
#pragma unroll
        for (int j = 0; j < 4; ++j)
          acc[i][j] = MFMA_F16(af[i], bfr[j], acc[i][j]);
    }
  }

  float s[4], s2[4];
#pragma unroll
  for (int j = 0; j < 4; ++j) { s[j] = 0.f; s2[j] = 0.f; }
#pragma unroll
  for (int i = 0; i < 4; ++i) {
#pragma unroll
    for (int r = 0; r < 4; ++r) {
      int c = c0w + i * 16 + q4 * 4 + r;
      const float* rp = resid + ((size_t)b * 256 + c) * 16384 + p0;
#pragma unroll
      for (int j = 0; j < 4; ++j) {
        float v = acc[i][j][r] + rp[j * 16 + l15];
        acc[i][j][r] = v;
        s[j] += v; s2[j] += v * v;
      }
    }
  }
#pragma unroll
  for (int j = 0; j < 4; ++j) {
    s[j]  += __shfl_xor(s[j], 16);
    s[j]  += __shfl_xor(s[j], 32);
    s2[j] += __shfl_xor(s2[j], 16);
    s2[j] += __shfl_xor(s2[j], 32);
  }
  if (q4 == 0) {
#pragma unroll
    for (int j = 0; j < 4; ++j) {
      red[0][wv][j * 16 + l15] = s[j];
      red[1][wv][j * 16 + l15] = s2[j];
    }
  }
  __syncthreads();
#pragma unroll
  for (int j = 0; j < 4; ++j) {
    int pl = j * 16 + l15;
    float ts  = red[0][0][pl] + red[0][1][pl] + red[0][2][pl] + red[0][3][pl];
    float ts2 = red[1][0][pl] + red[1][1][pl] + red[1][2][pl] + red[1][3][pl];
    float mean = ts * (1.f / 256.f);
    float var  = ts2 * (1.f / 256.f) - mean * mean;
    float rstd = rsqrtf(var + 1e-6f);
#pragma unroll
    for (int i = 0; i < 4; ++i) {
#pragma unroll
      for (int r = 0; r < 4; ++r) {
        int c = c0w + i * 16 + q4 * 4 + r;
        outp[((size_t)b * 256 + c) * 16384 + p0 + pl] =
            (acc[i][j][r] - mean) * rstd * lnws[c] + lnbs[c];
      }
    }
  }
}

// ---------------------------------------------------------------------------
extern "C" void kernel_launch(void* const* d_in, const int* in_sizes, int n_in,
                              void* d_out, int out_size, void* d_ws, size_t ws_size,
                              hipStream_t stream) {
  const float* q   = (const float*)d_in[0];
  const float* k   = (const float*)d_in[1];
  const float* v   = (const float*)d_in[2];
  const float* Wq  = (const float*)d_in[3];
  const float* Wk  = (const float*)d_in[4];
  const float* Wv  = (const float*)d_in[5];
  const float* Wfc = (const float*)d_in[6];
  const float* lnw = (const float*)d_in[7];
  const float* lnb = (const float*)d_in[8];
  float* outp = (float*)d_out;

  // workspace: 4 x 64 MiB f16 regions; W_f16 copies overlay dead regions:
  //   Wqkv_f16 -> head of ao region (dead until attn rewrites it fully)
  //   Wfc_f16  -> head of qh region (dead after attn)
  f16_t* qh = (f16_t*)d_ws;
  f16_t* kh = qh + 33554432ULL;
  f16_t* vh = kh + 33554432ULL;
  f16_t* ao = vh + 33554432ULL;
  f16_t* Wqkv16 = ao;   // 393216 f16, consumed by proj before attn writes ao
  f16_t* Wfc16  = qh;   // 131072 f16, written after attn, consumed by fc_ln

  wconvA_kernel<<<dim3(384), dim3(256), 0, stream>>>(Wq, Wk, Wv, Wqkv16);
  proj_kernel<<<dim3(1536), dim3(256), 0, stream>>>(q, k, v, Wqkv16, qh, kh, vh);
  attn_kernel<<<dim3(1024), dim3(512), 0, stream>>>(qh, kh, vh, ao);
  wconvB_kernel<<<dim3(128), dim3(256), 0, stream>>>(Wfc, Wfc16);
  fc_ln_kernel<<<dim3(1024), dim3(256), 0, stream>>>(ao, Wfc16, q, lnw, lnb, outp);
}

// Round 2
// 838.353 us; speedup vs baseline: 2.6064x; 2.6064x over previous
//
#include <hip/hip_runtime.h>
#include <hip/hip_bf16.h>
#include <cstdint>
#include <cstddef>

typedef _Float16 f16_t;
typedef _Float16 h2    __attribute__((ext_vector_type(2)));
typedef _Float16 f16x8 __attribute__((ext_vector_type(8)));
typedef float    f32x4 __attribute__((ext_vector_type(4)));

#define MFMA_F16(A, Bv, Cv) __builtin_amdgcn_mfma_f32_16x16x32_f16((A), (Bv), (Cv), 0, 0, 0)

__device__ __forceinline__ float fdot2_(h2 a, h2 b, float c) {
#if __has_builtin(__builtin_amdgcn_fdot2)
  return __builtin_amdgcn_fdot2(a, b, c, false);
#else
  return c + (float)a[0] * (float)b[0] + (float)a[1] * (float)b[1];
#endif
}

// ---------------------------------------------------------------------------
// W fp32 -> f16 converters (run while target ws region is dead).
// ---------------------------------------------------------------------------
__global__ __launch_bounds__(256) void wconvA_kernel(
    const float* __restrict__ Wq, const float* __restrict__ Wk,
    const float* __restrict__ Wv, f16_t* __restrict__ dst)
{
  int idx = blockIdx.x * 256 + threadIdx.x;        // 98304 float4 tasks
  int src = idx >> 15, off = idx & 32767;
  const float* W = (src == 0) ? Wq : (src == 1) ? Wk : Wv;
  float4 a = *(const float4*)(W + (size_t)off * 4);
  f16_t* d = dst + (size_t)src * 131072 + (size_t)off * 4;
  d[0] = (f16_t)a.x; d[1] = (f16_t)a.y; d[2] = (f16_t)a.z; d[3] = (f16_t)a.w;
}

__global__ __launch_bounds__(256) void wconvB_kernel(
    const float* __restrict__ Wfc, f16_t* __restrict__ dst)
{
  int idx = blockIdx.x * 256 + threadIdx.x;        // 32768 float4 tasks
  float4 a = *(const float4*)(Wfc + (size_t)idx * 4);
  f16_t* d = dst + (size_t)idx * 4;
  d[0] = (f16_t)a.x; d[1] = (f16_t)a.y; d[2] = (f16_t)a.z; d[3] = (f16_t)a.w;
}

// ---------------------------------------------------------------------------
// Stage A: projections.  Block = 128 pixels; X staged ONCE (64 KB LDS, f16,
// [p][k=256] with chunk swizzle g ^ (p&7) ^ ((p>>3)&7)); loop 4 otiles inside;
// B-fragments gathered directly from L2-hot W_f16 (no LDS, no barriers).
// grid: [3 proj][4 b][128 ptile] = 1536 blocks x 256 thr
// ---------------------------------------------------------------------------
__global__ __launch_bounds__(256, 2) void proj_kernel(
    const float* __restrict__ xq, const float* __restrict__ xk, const float* __restrict__ xv,
    const f16_t* __restrict__ Wall,
    f16_t* __restrict__ qh, f16_t* __restrict__ kh, f16_t* __restrict__ vh)
{
  int bid = blockIdx.x;
  const int pt = bid & 127; bid >>= 7;
  const int b  = bid & 3;   bid >>= 2;
  const int proj = bid;

  const float* X = (proj == 0) ? xq : (proj == 1) ? xk : xv;
  const f16_t* Wf = Wall + (size_t)proj * 131072;
  f16_t* OUT     = (proj == 0) ? qh : (proj == 1) ? kh : vh;

  const int p0 = pt * 128;
  __shared__ __align__(16) f16_t Xl[128 * 256];  // 64 KB

  const int tid = threadIdx.x;
  const int lane = tid & 63, wv = tid >> 6;
  const int wp = (wv & 1) * 64, wo = (wv >> 1) * 64;
  const int l15 = lane & 15, q4 = lane >> 4;

  const size_t xbase = (size_t)b * 256 * 16384;

  // stage X tile [c=256][p=128] fp32 -> LDS [p][k] f16, c-pairs as h2
#pragma unroll
  for (int t = 0; t < 16; ++t) {
    int task = t * 256 + tid;            // 4096 tasks: (c2 128) x (p4 32)
    int c2 = task >> 5, p4 = task & 31;
    int c0 = c2 * 2;
    float4 a0 = *(const float4*)(X + xbase + (size_t)c0 * 16384 + p0 + p4 * 4);
    float4 a1 = *(const float4*)(X + xbase + (size_t)(c0 + 1) * 16384 + p0 + p4 * 4);
    const float* f0 = &a0.x; const float* f1 = &a1.x;
    int g = c0 >> 3;
#pragma unroll
    for (int i = 0; i < 4; ++i) {
      int p = p4 * 4 + i;
      int sw = (p & 7) ^ ((p >> 3) & 7);
      h2 val = (h2){(f16_t)f0[i], (f16_t)f1[i]};
      *(h2*)&Xl[(p << 8) + ((g ^ sw) << 3) + (c0 & 7)] = val;
    }
  }
  __syncthreads();

#pragma unroll 1
  for (int ot = 0; ot < 4; ++ot) {
    f32x4 acc[4][4];
#pragma unroll
    for (int i = 0; i < 4; ++i)
#pragma unroll
      for (int j = 0; j < 4; ++j) acc[i][j] = (f32x4){0.f, 0.f, 0.f, 0.f};

#pragma unroll
    for (int kc = 0; kc < 4; ++kc) {
#pragma unroll
      for (int ks = 0; ks < 2; ++ks) {
        const int gq = kc * 8 + ks * 4 + q4;     // chunk 0..31
        f16x8 af[4], bfr[4];
#pragma unroll
        for (int i = 0; i < 4; ++i) {
          int p = wp + i * 16 + l15;
          int sw = (p & 7) ^ ((p >> 3) & 7);
          int gs = (gq & 0x18) | ((gq ^ sw) & 7);
          af[i] = *(const f16x8*)&Xl[(p << 8) + (gs << 3)];
        }
#pragma unroll
        for (int j = 0; j < 4; ++j) {
          int o = ot * 128 + wo + j * 16 + l15;
          bfr[j] = *(const f16x8*)(Wf + (size_t)o * 256 + kc * 64 + ks * 32 + q4 * 8);
        }
#pragma unroll
        for (int i = 0; i < 4; ++i)
#pragma unroll
          for (int j = 0; j < 4; ++j)
            acc[i][j] = MFMA_F16(af[i], bfr[j], acc[i][j]);
      }
    }

#pragma unroll
    for (int i = 0; i < 4; ++i) {
#pragma unroll
      for (int j = 0; j < 4; ++j) {
        int o = ot * 128 + wo + j * 16 + l15;
        int nn = o >> 6, d = o & 63;
#pragma unroll
        for (int r = 0; r < 4; ++r) {
          int p = p0 + wp + i * 16 + q4 * 4 + r;
          OUT[(((size_t)b * 8 + nn) * 16384 + p) * 64 + d] = (f16_t)acc[i][j][r];
        }
      }
    }
  }
}

// ---------------------------------------------------------------------------
// Stage B: 7x7 local attention, online softmax, dy-paired.
// v3: 8 pixel rows per block (halo re-fetch 14/8 vs v1's 12/4), 512 threads =
// (rp 4, w 64, dg 2); v1-style direct global->LDS prefetch into the other
// ring slot (NO reg staging -> low VGPR), __launch_bounds__(512,4) gives the
// allocator 128 VGPRs so it cannot spill (LDS caps occupancy at 4 blocks/CU
// anyway; VGPR<=64 would give 32 waves/CU).
// 2-slot LDS ring of K|V rows (70 px x 16 chunks x 16B, XOR swizzle); 14 its.
// Zero halo == reference zero padding (OOB logits 0 participate in softmax).
// grid: [4 b][8 n][16 rowoct][2 whalf] = 1024 blocks x 512 thr
// ---------------------------------------------------------------------------
__global__ __launch_bounds__(512, 4) void attn_kernel(
    const f16_t* __restrict__ qh, const f16_t* __restrict__ kh,
    const f16_t* __restrict__ vh, f16_t* __restrict__ ao)
{
  int bid = blockIdx.x;
  const int wh = bid & 1;  bid >>= 1;
  const int oc8 = bid & 15; bid >>= 4;
  const int n  = bid & 7;  bid >>= 3;
  const int b  = bid;
  const int h0 = oc8 * 8, w0 = wh * 64;

  const int tid = threadIdx.x;
  const int rp = tid >> 7;          // row-pair 0..3 (wave-uniform)
  const int w  = (tid >> 1) & 63;
  const int dg = tid & 1;           // 32-channel group
  const int dg4 = dg * 4;
  const int hA = h0 + 2 * rp, hB = hA + 1;

  const size_t headoff = ((size_t)b * 8 + n) * 16384 * 64;
  const f16_t* Qh = qh + headoff;
  const f16_t* Kh = kh + headoff;
  const f16_t* Vh = vh + headoff;

  __shared__ uint4 ring[2][70 * 16];  // [slot][pix*16 + (oc ^ (pix&15))]

  union Pack { uint4 u[4]; h2 h[16]; };

  Pack quA, quB;
  {
    const uint4* qa = (const uint4*)(Qh + ((size_t)hA * 128 + w0 + w) * 64 + dg * 32);
    const uint4* qb = (const uint4*)(Qh + ((size_t)hB * 128 + w0 + w) * 64 + dg * 32);
#pragma unroll
    for (int j = 0; j < 4; ++j) { quA.u[j] = qa[j]; quB.u[j] = qb[j]; }
  }

  auto load_row = [&](int r, int slot) {
    const bool rok = (r >= 0) && (r < 128);
#pragma unroll
    for (int t = 0; t < 3; ++t) {
      int task = t * 512 + tid;            // 70*16 = 1120 16B-chunk tasks
      if (task < 1120) {
        int pix = task >> 4, oc = task & 15;
        int ww = w0 + pix - 3;
        uint4 val = make_uint4(0u, 0u, 0u, 0u);
        if (rok && ww >= 0 && ww < 128) {
          const f16_t* src = (oc < 8)
              ? (Kh + ((size_t)r * 128 + ww) * 64 + oc * 8)
              : (Vh + ((size_t)r * 128 + ww) * 64 + (oc - 8) * 8);
          val = *(const uint4*)src;
        }
        ring[slot][(pix << 4) + (oc ^ (pix & 15))] = val;
      }
    }
  };

  const float cscale = 0.18033688011112042f;  // (1/8) * log2(e)

  float mA = -3.0e38f, lA = 0.f, mB = -3.0e38f, lB = 0.f;
  h2 ovA[16], ovB[16];
#pragma unroll
  for (int j = 0; j < 16; ++j) { ovA[j] = (h2){(f16_t)0.f, (f16_t)0.f}; ovB[j] = ovA[j]; }

  load_row(h0 - 3, 0);
  __syncthreads();

#pragma unroll 1
  for (int it = 0; it < 14; ++it) {
    if (it < 13) load_row(h0 - 2 + it, (it + 1) & 1);  // prefetch next row
    const uint4* cur = ring[it & 1];
    const int dyA = it - 2 * rp;                        // wave-uniform
    const int dyB = dyA - 1;
    const bool aA = (dyA >= 0) && (dyA < 7);
    const bool aB = (dyB >= 0) && (dyB < 7);
    if (aA || aB) {
      // ---- scores vs this k-row for both owned pixels ----
      float sA[7], sB[7];
#pragma unroll
      for (int dx = 0; dx < 7; ++dx) {
        const int pix = w + dx, sw = pix & 15, base = pix << 4;
        Pack ku;
        ku.u[0] = cur[base + ((dg4 + 0) ^ sw)];
        ku.u[1] = cur[base + ((dg4 + 1) ^ sw)];
        ku.u[2] = cur[base + ((dg4 + 2) ^ sw)];
        ku.u[3] = cur[base + ((dg4 + 3) ^ sw)];
        float accA = 0.f, accB = 0.f;
#pragma unroll
        for (int j = 0; j < 16; ++j) {
          accA = fdot2_(quA.h[j], ku.h[j], accA);
          accB = fdot2_(quB.h[j], ku.h[j], accB);
        }
        sA[dx] = accA; sB[dx] = accB;
      }
#pragma unroll
      for (int dx = 0; dx < 7; ++dx) {
        sA[dx] = (sA[dx] + __shfl_xor(sA[dx], 1)) * cscale;
        sB[dx] = (sB[dx] + __shfl_xor(sB[dx], 1)) * cscale;
      }

      // ---- online softmax updates ----
      h2 eA[7], eB[7];
      if (aA) {
        float nm = mA;
#pragma unroll
        for (int dx = 0; dx < 7; ++dx) nm = fmaxf(nm, sA[dx]);
        float alpha = exp2f(mA - nm);
        mA = nm; lA *= alpha;
        f16_t ah = (f16_t)alpha; h2 a2 = (h2){ah, ah};
#pragma unroll
        for (int j = 0; j < 16; ++j) ovA[j] *= a2;
#pragma unroll
        for (int dx = 0; dx < 7; ++dx) {
          float e = exp2f(sA[dx] - mA);
          lA += e; f16_t eh = (f16_t)e; eA[dx] = (h2){eh, eh};
        }
      }
      if (aB) {
        float nm = mB;
#pragma unroll
        for (int dx = 0; dx < 7; ++dx) nm = fmaxf(nm, sB[dx]);
        float alpha = exp2f(mB - nm);
        mB = nm; lB *= alpha;
        f16_t ah = (f16_t)alpha; h2 a2 = (h2){ah, ah};
#pragma unroll
        for (int j = 0; j < 16; ++j) ovB[j] *= a2;
#pragma unroll
        for (int dx = 0; dx < 7; ++dx) {
          float e = exp2f(sB[dx] - mB);
          lB += e; f16_t eh = (f16_t)e; eB[dx] = (h2){eh, eh};
        }
      }

      // ---- weighted V (chunk read shared by both pixels) ----
#pragma unroll
      for (int dx = 0; dx < 7; ++dx) {
        const int pix = w + dx, sw = pix & 15, base = pix << 4;
        Pack vu;
        vu.u[0] = cur[base + ((8 + dg4 + 0) ^ sw)];
        vu.u[1] = cur[base + ((8 + dg4 + 1) ^ sw)];
        vu.u[2] = cur[base + ((8 + dg4 + 2) ^ sw)];
        vu.u[3] = cur[base + ((8 + dg4 + 3) ^ sw)];
        if (aA) {
#pragma unroll
          for (int j = 0; j < 16; ++j) ovA[j] = eA[dx] * vu.h[j] + ovA[j];
        }
        if (aB) {
#pragma unroll
          for (int j = 0; j < 16; ++j) ovB[j] = eB[dx] * vu.h[j] + ovB[j];
        }
      }
    }
    __syncthreads();
  }

  // epilogue: normalize, store 32 f16 channels per owned pixel
  {
    float inv = 1.0f / lA; f16_t ih = (f16_t)inv; h2 i2 = (h2){ih, ih};
    Pack ou;
#pragma unroll
    for (int j = 0; j < 16; ++j) ou.h[j] = ovA[j] * i2;
    uint4* d4 = (uint4*)(ao + (((size_t)b * 16384) + (size_t)hA * 128 + (w0 + w)) * 512 + n * 64 + dg * 32);
    d4[0] = ou.u[0]; d4[1] = ou.u[1]; d4[2] = ou.u[2]; d4[3] = ou.u[3];
  }
  {
    float inv = 1.0f / lB; f16_t ih = (f16_t)inv; h2 i2 = (h2){ih, ih};
    Pack ou;
#pragma unroll
    for (int j = 0; j < 16; ++j) ou.h[j] = ovB[j] * i2;
    uint4* d4 = (uint4*)(ao + (((size_t)b * 16384) + (size_t)hB * 128 + (w0 + w)) * 512 + n * 64 + dg * 32);
    d4[0] = ou.u[0]; d4[1] = ou.u[1]; d4[2] = ou.u[2]; d4[3] = ou.u[3];
  }
}

// ---------------------------------------------------------------------------
// Stage C: o = Wfc @ ao + residual, LayerNorm over C=256, fused.
// ao tile staged ONCE ([p=64][k=512] f16, 64 KB); A-fragments of Wfc_f16
// gathered directly from L2-hot global.  2 barriers/block.
// grid: [4 b][256 ptile(64)] = 1024 blocks x 256 thr
// ---------------------------------------------------------------------------
__global__ __launch_bounds__(256, 2) void fc_ln_kernel(
    const f16_t* __restrict__ ao, const f16_t* __restrict__ Wfc16,
    const float* __restrict__ resid, const float* __restrict__ lnw,
    const float* __restrict__ lnb, float* __restrict__ outp)
{
  int bid = blockIdx.x;
  const int pt = bid & 255;
  const int b = bid >> 8;
  const int p0 = pt * 64;

  const int tid = threadIdx.x;
  const int lane = tid & 63, wv = tid >> 6;
  const int c0w = wv * 64;
  const int l15 = lane & 15, q4 = lane >> 4;

  __shared__ __align__(16) f16_t Bl[64 * 512];  // ao tile [p][k], 64 KB
  __shared__ float lnws[256], lnbs[256];
  __shared__ float red[2][4][64];

  lnws[tid] = lnw[tid];
  lnbs[tid] = lnb[tid];

  // stage full ao tile once
#pragma unroll
  for (int t = 0; t < 16; ++t) {
    int task = t * 256 + tid;            // 4096 tasks: (p 64) x (g 64)
    int p = task >> 6, g = task & 63;
    uint4 v4 = *(const uint4*)(ao + ((size_t)b * 16384 + p0 + p) * 512 + g * 8);
    int gs = (g & 0x38) | ((g ^ (p & 7)) & 7);
    *(uint4*)&Bl[(p << 9) + (gs << 3)] = v4;
  }
  __syncthreads();

  f32x4 acc[4][4];
#pragma unroll
  for (int i = 0; i < 4; ++i)
#pragma unroll
    for (int j = 0; j < 4; ++j) acc[i][j] = (f32x4){0.f, 0.f, 0.f, 0.f};

#pragma unroll 1
  for (int kc = 0; kc < 8; ++kc) {
#pragma unroll
    for (int ks = 0; ks < 2; ++ks) {
      const int gq = kc * 8 + ks * 4 + q4;     // chunk 0..63
      f16x8 af[4], bfr[4];
#pragma unroll
      for (int i = 0; i < 4; ++i) {
        int c = c0w + i * 16 + l15;
        af[i] = *(const f16x8*)(Wfc16 + (size_t)c * 512 + kc * 64 + ks * 32 + q4 * 8);
      }
#pragma unroll
      for (int j = 0; j < 4; ++j) {
        int p = j * 16 + l15;
        int gs = (gq & 0x38) | ((gq ^ (p & 7)) & 7);
        bfr[j] = *(const f16x8*)&Bl[(p << 9) + (gs << 3)];
      }
#pragma unroll
      for (int i = 0; i < 4; ++i)
#pragma unroll
        for (int j = 0; j < 4; ++j)
          acc[i][j] = MFMA_F16(af[i], bfr[j], acc[i][j]);
    }
  }

  float s[4], s2[4];
#pragma unroll
  for (int j = 0; j < 4; ++j) { s[j] = 0.f; s2[j] = 0.f; }
#pragma unroll
  for (int i = 0; i < 4; ++i) {
#pragma unroll
    for (int r = 0; r < 4; ++r) {
      int c = c0w + i * 16 + q4 * 4 + r;
      const float* rp = resid + ((size_t)b * 256 + c) * 16384 + p0;
#pragma unroll
      for (int j = 0; j < 4; ++j) {
        float v = acc[i][j][r] + rp[j * 16 + l15];
        acc[i][j][r] = v;
        s[j] += v; s2[j] += v * v;
      }
    }
  }
#pragma unroll
  for (int j = 0; j < 4; ++j) {
    s[j]  += __shfl_xor(s[j], 16);
    s[j]  += __shfl_xor(s[j], 32);
    s2[j] += __shfl_xor(s2[j], 16);
    s2[j] += __shfl_xor(s2[j], 32);
  }
  if (q4 == 0) {
#pragma unroll
    for (int j = 0; j < 4; ++j) {
      red[0][wv][j * 16 + l15] = s[j];
      red[1][wv][j * 16 + l15] = s2[j];
    }
  }
  __syncthreads();
#pragma unroll
  for (int j = 0; j < 4; ++j) {
    int pl = j * 16 + l15;
    float ts  = red[0][0][pl] + red[0][1][pl] + red[0][2][pl] + red[0][3][pl];
    float ts2 = red[1][0][pl] + red[1][1][pl] + red[1][2][pl] + red[1][3][pl];
    float mean = ts * (1.f / 256.f);
    float var  = ts2 * (1.f / 256.f) - mean * mean;
    float rstd = rsqrtf(var + 1e-6f);
#pragma unroll
    for (int i = 0; i < 4; ++i) {
#pragma unroll
      for (int r = 0; r < 4; ++r) {
        int c = c0w + i * 16 + q4 * 4 + r;
        outp[((size_t)b * 256 + c) * 16384 + p0 + pl] =
            (acc[i][j][r] - mean) * rstd * lnws[c] + lnbs[c];
      }
    }
  }
}

// ---------------------------------------------------------------------------
extern "C" void kernel_launch(void* const* d_in, const int* in_sizes, int n_in,
                              void* d_out, int out_size, void* d_ws, size_t ws_size,
                              hipStream_t stream) {
  const float* q   = (const float*)d_in[0];
  const float* k   = (const float*)d_in[1];
  const float* v   = (const float*)d_in[2];
  const float* Wq  = (const float*)d_in[3];
  const float* Wk  = (const float*)d_in[4];
  const float* Wv  = (const float*)d_in[5];
  const float* Wfc = (const float*)d_in[6];
  const float* lnw = (const float*)d_in[7];
  const float* lnb = (const float*)d_in[8];
  float* outp = (float*)d_out;

  // workspace: 4 x 64 MiB f16 regions; W_f16 copies overlay dead regions:
  //   Wqkv_f16 -> head of ao region (dead until attn rewrites it fully)
  //   Wfc_f16  -> head of qh region (dead after attn)
  f16_t* qh = (f16_t*)d_ws;
  f16_t* kh = qh + 33554432ULL;
  f16_t* vh = kh + 33554432ULL;
  f16_t* ao = vh + 33554432ULL;
  f16_t* Wqkv16 = ao;   // 393216 f16, consumed by proj before attn writes ao
  f16_t* Wfc16  = qh;   // 131072 f16, written after attn, consumed by fc_ln

  wconvA_kernel<<<dim3(384), dim3(256), 0, stream>>>(Wq, Wk, Wv, Wqkv16);
  proj_kernel<<<dim3(1536), dim3(256), 0, stream>>>(q, k, v, Wqkv16, qh, kh, vh);
  attn_kernel<<<dim3(1024), dim3(512), 0, stream>>>(qh, kh, vh, ao);
  wconvB_kernel<<<dim3(128), dim3(256), 0, stream>>>(Wfc, Wfc16);
  fc_ln_kernel<<<dim3(1024), dim3(256), 0, stream>>>(ao, Wfc16, q, lnw, lnb, outp);
}